// Round 7
// baseline (1015.175 us; speedup 1.0000x reference)
//
#include <hip/hip_runtime.h>

typedef short short8 __attribute__((ext_vector_type(8)));
typedef float f32x4 __attribute__((ext_vector_type(4)));
typedef float fv2 __attribute__((ext_vector_type(2)));
typedef unsigned int u32;

#define HDIM 128
#define NSPLIT 32
#define CAP 64          // bucket capacity per row; rows ~Poisson(16), P(>64) ~ 1e-20

#define AS1 __attribute__((address_space(1)))
#define AS3 __attribute__((address_space(3)))

__device__ __forceinline__ void gload16(const void* g, void* l) {
  __builtin_amdgcn_global_load_lds((AS1 const u32*)g, (AS3 u32*)l, 16, 0, 0);
}

__device__ __forceinline__ unsigned short f2bf(float x) {
  unsigned int u = __float_as_uint(x);
  unsigned int r = (u + 0x7fffu + ((u >> 16) & 1u)) >> 16;
  return (unsigned short)r;
}
__device__ __forceinline__ float bf2f(unsigned short b) {
  return __uint_as_float(((unsigned int)b) << 16);
}

#define MFMA(a, b, c) __builtin_amdgcn_mfma_f32_16x16x32_bf16(a, b, c, 0, 0, 0)

// ===========================================================================
// DIAGNOSTIC ROUND (R7): fused_glp and gemm re-execute their full work
// `reps`(=4) times per dispatch, with input base pointers laundered through an
// opaque asm zero-offset each rep (defeats cross-rep CSE/LICM; rule #17).
// All stores rewrite bit-identical values -> output unchanged, but dispatch
// duration = reps x true kernel time, pushing both kernels above the 145 us
// poison-fills into the rocprof top-5 WITH their counters.
// Remove the rep loops (reps=1) once attribution is done.
// ===========================================================================

// ---------------------------------------------------------------------------
// 1) bucket placement (R3 layout): p = atomicAdd(cnt[r]); se[r*CAP+p]={c,v}.
//    (not repeated: atomics are not idempotent)
// ---------------------------------------------------------------------------
__global__ __launch_bounds__(256) void bucket_kernel(
    const int* __restrict__ r0, const int* __restrict__ c0, const float* __restrict__ v0,
    const int* __restrict__ r1, const int* __restrict__ c1, const float* __restrict__ v1,
    int* __restrict__ cnt0, int* __restrict__ cnt1,
    int2* __restrict__ se0, int2* __restrict__ se1, int E)
{
  int t = blockIdx.x * 256 + threadIdx.x;
  if (t < E) {
    int r = r0[t];
    int p = atomicAdd(&cnt0[r], 1);
    if (p < CAP) se0[(size_t)r * CAP + p] = make_int2(c0[t], __float_as_int(v0[t]));
  } else if (t < 2 * E) {
    int e = t - E;
    int r = r1[e];
    int p = atomicAdd(&cnt1[r], 1);
    if (p < CAP) se1[(size_t)r * CAP + p] = make_int2(c1[e], __float_as_int(v1[e]));
  }
}

// ---------------------------------------------------------------------------
// 2) FUSED gather + LN + bf16 hi/lo pack (R3 best form, fv2 gather),
//    wrapped in the diagnostic rep loop.
// ---------------------------------------------------------------------------
__global__ __launch_bounds__(1024) void fused_glp_kernel(
    const float* __restrict__ Wn0, const float* __restrict__ Wn1,
    const float* __restrict__ W0s, const float* __restrict__ W1s,
    const int* __restrict__ cnt0, const int2* __restrict__ se0,
    const int* __restrict__ cnt1, const int2* __restrict__ se1,
    const float* __restrict__ gamma, const float* __restrict__ beta,
    unsigned short* __restrict__ ph, unsigned short* __restrict__ pl, int V,
    int reps)
{
  __shared__ __align__(16) unsigned short lh[2048];   // 4 KB hi half-tile
  __shared__ __align__(16) unsigned short ll[2048];   // 4 KB lo half-tile
  int t = threadIdx.x;
  int wv = t >> 6, lane = t & 63;
  int g = blockIdx.x >> 1, hs = blockIdx.x & 1;

  if (t < 256)      ((f32x4*)lh)[t] = (f32x4)(0.f);
  else if (t < 512) ((f32x4*)ll)[t - 256] = (f32x4)(0.f);
  __syncthreads();

  int v = g * 32 + hs * 16 + wv;
  int h = lane * 2;
  if (v < V) {
    fv2 gm = ((const fv2*)gamma)[lane];
    fv2 bt = ((const fv2*)beta)[lane];

    for (int rep = 0; rep < reps; ++rep) {
      // opaque zero-offset: all derived addresses look rep-dependent
      uintptr_t zo = 0;
      asm volatile("" : "+v"(zo));
      const float* Wn0r = (const float*)((const char*)Wn0 + zo);
      const float* Wn1r = (const float*)((const char*)Wn1 + zo);
      const float* W0sr = (const float*)((const char*)W0s + zo);
      const float* W1sr = (const float*)((const char*)W1s + zo);
      const int*  cnt0r = (const int*)((const char*)cnt0 + zo);
      const int*  cnt1r = (const int*)((const char*)cnt1 + zo);
      const int2* se0r  = (const int2*)((const char*)se0 + zo);
      const int2* se1r  = (const int2*)((const char*)se1 + zo);

      float ry0 = 0.f, ry1 = 0.f;
      #pragma unroll
      for (int br = 0; br < 2; ++br) {
        const float* Wn = br ? Wn1r : Wn0r;
        const float* Ws = br ? W1sr : W0sr;
        const int* cnt  = br ? cnt1r : cnt0r;
        const int2* se  = br ? se1r : se0r;
        int n = cnt[v]; if (n > CAP) n = CAP;
        const int2* sep = se + (size_t)v * CAP;
        float a0 = 0.f, a1 = 0.f, dsum = 0.f;
        int i = 0;
        for (; i + 4 <= n; i += 4) {
          int2 e0 = sep[i], e1 = sep[i + 1], e2 = sep[i + 2], e3 = sep[i + 3];
          fv2 w0 = ((const fv2*)(Wn + (size_t)e0.x * HDIM))[lane];
          fv2 w1 = ((const fv2*)(Wn + (size_t)e1.x * HDIM))[lane];
          fv2 w2 = ((const fv2*)(Wn + (size_t)e2.x * HDIM))[lane];
          fv2 w3 = ((const fv2*)(Wn + (size_t)e3.x * HDIM))[lane];
          float f0 = __int_as_float(e0.y), f1 = __int_as_float(e1.y);
          float f2 = __int_as_float(e2.y), f3 = __int_as_float(e3.y);
          dsum += (f0 + f1) + (f2 + f3);
          a0 = fmaf(f0, w0.x, a0); a1 = fmaf(f0, w0.y, a1);
          a0 = fmaf(f1, w1.x, a0); a1 = fmaf(f1, w1.y, a1);
          a0 = fmaf(f2, w2.x, a0); a1 = fmaf(f2, w2.y, a1);
          a0 = fmaf(f3, w3.x, a0); a1 = fmaf(f3, w3.y, a1);
        }
        for (; i < n; ++i) {
          int2 e0 = sep[i];
          fv2 w0 = ((const fv2*)(Wn + (size_t)e0.x * HDIM))[lane];
          float f0 = __int_as_float(e0.y);
          dsum += f0;
          a0 = fmaf(f0, w0.x, a0); a1 = fmaf(f0, w0.y, a1);
        }
        float invd = 1.0f / fmaxf(dsum, 1.0f);
        fv2 ww = ((const fv2*)(Ws + (size_t)v * HDIM))[lane];
        float x0 = fmaxf(fmaf(a0, invd, ww.x), 0.f);
        float x1 = fmaxf(fmaf(a1, invd, ww.y), 0.f);
        float sum = x0 + x1;
        #pragma unroll
        for (int off = 32; off; off >>= 1) sum += __shfl_xor(sum, off, 64);
        float mu = sum * (1.0f / 128.0f);
        float d0 = x0 - mu, d1 = x1 - mu;
        float q = d0 * d0 + d1 * d1;
        #pragma unroll
        for (int off = 32; off; off >>= 1) q += __shfl_xor(q, off, 64);
        float rstd = rsqrtf(q * (1.0f / 128.0f) + 1e-5f);
        ry0 += d0 * rstd * gm.x + bt.x;
        ry1 += d1 * rstd * gm.y + bt.y;
      }
      // scatter (side effect consuming ry -> keeps each rep's compute live;
      // values bit-identical every rep)
      int tt = lane >> 3;
      int loc = tt * 256 + ((wv >> 3) * 16 + (h & 15)) * 8 + (wv & 7);
      unsigned short h0 = f2bf(ry0);
      unsigned short l0 = f2bf(ry0 - bf2f(h0));
      unsigned short h1 = f2bf(ry1);
      unsigned short l1 = f2bf(ry1 - bf2f(h1));
      lh[loc] = h0;     ll[loc] = l0;
      lh[loc + 8] = h1; ll[loc + 8] = l1;
    }
  }
  __syncthreads();

  // coalesced write-out: half-tile chunk c (16B) -> global chunk
  //   g*512 + (c>>5)*32 + hs*32 + c     (512 B runs, 512 B stride)
  if (t < 512) {
    int arr = t >> 8;            // 0: ph, 1: pl
    int c = t & 255;
    size_t chunk = (size_t)g * 512 + (size_t)(((c >> 5) + hs) * 32 + c);
    f32x4 val = arr ? ((const f32x4*)ll)[c] : ((const f32x4*)lh)[c];
    f32x4* dst = arr ? (f32x4*)pl : (f32x4*)ph;
    dst[chunk] = val;
  }
}

__device__ __forceinline__ void cvt8hi(float4 a0, float4 a1, short8& hi) {
  float vv[8] = {a0.x, a0.y, a0.z, a0.w, a1.x, a1.y, a1.z, a1.w};
  #pragma unroll
  for (int j = 0; j < 8; ++j) hi[j] = (short)f2bf(vv[j]);
}

// ---------------------------------------------------------------------------
// 3) MFMA GEMM (unchanged structure), wrapped in the diagnostic rep loop.
//    Per rep: launder bases, zero acc, full prologue+K-loop, epilogue store
//    (global store consumes acc each rep -> MFMAs not DCE'd; same values).
// ---------------------------------------------------------------------------
__global__ __launch_bounds__(256, 2) void gemm_kernel(
    const float* __restrict__ X, const unsigned short* __restrict__ ph,
    const unsigned short* __restrict__ pl, float* __restrict__ P,
    int M, int K, int groups, int gps, int reps)
{
  __shared__ __align__(16) float Xl[2][128 * 32];            // 16 KB each
  __shared__ __align__(16) unsigned short Bl[2][2][4096];    // hi/lo, 8 KB each
  int t = threadIdx.x;
  int w = t >> 6, lane = t & 63;
  int m0 = blockIdx.x * 128;
  int g0 = blockIdx.y * gps;
  int g1 = g0 + gps; if (g1 > groups) g1 = groups;
  int q = lane >> 4;

  int xr = w * 32 + (lane >> 3);          // local row for staging call j=0 (+8j)
  int xc = lane & 7;                      // 16B chunk index
  int swz = ((xc ^ (xr & 7)) << 2);

  for (int rep = 0; rep < reps; ++rep) {
    uintptr_t zo = 0;
    asm volatile("" : "+v"(zo));
    const float* Xr = (const float*)((const char*)X + zo);
    const unsigned short* phr = (const unsigned short*)((const char*)ph + zo);
    const unsigned short* plr = (const unsigned short*)((const char*)pl + zo);

    f32x4 acc[2][8];
    #pragma unroll
    for (int rt = 0; rt < 2; ++rt)
      #pragma unroll
      for (int ct = 0; ct < 8; ++ct) acc[rt][ct] = (f32x4)(0.f);

    auto stageX = [&](int g, int buf) {
      int kf = g * 32 + swz;
      bool ok = (kf + 4 <= K);
      const float* rbase = Xr + (size_t)(m0 + xr) * K + kf;
      #pragma unroll
      for (int j = 0; j < 4; ++j) {
        const float* gp = ok ? (rbase + (size_t)(8 * j) * K) : Xr;
        gload16(gp, &Xl[buf][(w * 32 + 8 * j) * 32]);
      }
    };
    auto stageB = [&](int g, int buf) {
      const unsigned short* gh = phr + (size_t)g * 4096 + (w * 2) * 512 + lane * 8;
      const unsigned short* gl = plr + (size_t)g * 4096 + (w * 2) * 512 + lane * 8;
      #pragma unroll
      for (int j = 0; j < 2; ++j) {
        gload16(gh + j * 512, &Bl[buf][0][(w * 2 + j) * 512]);
        gload16(gl + j * 512, &Bl[buf][1][(w * 2 + j) * 512]);
      }
    };

    if (g0 < g1) { stageX(g0, 0); stageB(g0, 0); }
    __syncthreads();

    for (int g = g0; g < g1; ++g) {
      int buf = (g - g0) & 1;
      if (g + 1 < g1) { stageX(g + 1, buf ^ 1); stageB(g + 1, buf ^ 1); }
      short8 ah[2];
      #pragma unroll
      for (int rt = 0; rt < 2; ++rt) {
        int arow = w * 32 + rt * 16 + (lane & 15);
        int sx = arow & 7;
        float4 a0 = *(const float4*)&Xl[buf][arow * 32 + (((2 * q) ^ sx) << 2)];
        float4 a1 = *(const float4*)&Xl[buf][arow * 32 + ((((2 * q) | 1) ^ sx) << 2)];
        cvt8hi(a0, a1, ah[rt]);
      }
      #pragma unroll
      for (int ct = 0; ct < 8; ++ct) {
        short8 bh = *(const short8*)&Bl[buf][0][ct * 512 + lane * 8];
        short8 bl = *(const short8*)&Bl[buf][1][ct * 512 + lane * 8];
        #pragma unroll
        for (int rt = 0; rt < 2; ++rt) {
          acc[rt][ct] = MFMA(ah[rt], bh, acc[rt][ct]);
          acc[rt][ct] = MFMA(ah[rt], bl, acc[rt][ct]);
        }
      }
      __syncthreads();
    }

    float* pp = P + (size_t)blockIdx.y * ((size_t)M * 128);
    #pragma unroll
    for (int rt = 0; rt < 2; ++rt) {
      #pragma unroll
      for (int ct = 0; ct < 8; ++ct) {
        int n = ct * 16 + (lane & 15);
        #pragma unroll
        for (int r = 0; r < 4; ++r) {
          int m = m0 + w * 32 + rt * 16 + (lane >> 4) * 4 + r;
          pp[(size_t)m * 128 + n] = acc[rt][ct][r];
        }
      }
    }
  }
}

// ---------------------------------------------------------------------------
// 4) fused split-K reduce + fc (unchanged, not repeated: small)
// ---------------------------------------------------------------------------
__global__ __launch_bounds__(256) void fc_kernel(
    const float* __restrict__ P, const float* __restrict__ W,
    const float* __restrict__ bias, float* __restrict__ out, int n, int S)
{
  __shared__ float Wl[HDIM * HDIM];   // 64 KB
  __shared__ float Tl[16 * HDIM];     // 8 KB
  int t = threadIdx.x;
  const float4* Wv = (const float4*)W;
  float4* Wlv = (float4*)Wl;
  #pragma unroll
  for (int i = t; i < HDIM * HDIM / 4; i += 256) Wlv[i] = Wv[i];

  int m_loc = t >> 4;                 // 0..15
  int o = (t & 15) << 3;              // 0,8,..,120
  int m = blockIdx.x * 16 + m_loc;
  size_t base = (size_t)m * HDIM + o;

  float4 tv0 = make_float4(0.f, 0.f, 0.f, 0.f);
  float4 tv1 = make_float4(0.f, 0.f, 0.f, 0.f);
  for (int s = 0; s < S; ++s) {
    const float4* pr = (const float4*)(P + (size_t)s * n + base);
    float4 a = pr[0], b = pr[1];
    tv0.x += a.x; tv0.y += a.y; tv0.z += a.z; tv0.w += a.w;
    tv1.x += b.x; tv1.y += b.y; tv1.z += b.z; tv1.w += b.w;
  }
  ((float4*)&Tl[m_loc * HDIM + o])[0] = tv0;
  ((float4*)&Tl[m_loc * HDIM + o])[1] = tv1;
  __syncthreads();

  float acc[8];
  #pragma unroll
  for (int j = 0; j < 8; ++j) acc[j] = bias[o + j];
  const float* Trow = Tl + m_loc * HDIM;
  for (int k = 0; k < HDIM; ++k) {
    float a = Trow[k];
    const float* wr = &Wl[k * HDIM + o];
    #pragma unroll
    for (int j = 0; j < 8; ++j) acc[j] = fmaf(a, wr[j], acc[j]);
  }
  float* orow = out + (size_t)m * HDIM + o;
  #pragma unroll
  for (int j = 0; j < 8; ++j) orow[j] = acc[j];
}

// ---------------------------------------------------------------------------
extern "C" void kernel_launch(void* const* d_in, const int* in_sizes, int n_in,
                              void* d_out, int out_size, void* d_ws, size_t ws_size,
                              hipStream_t stream) {
  const float* X   = (const float*)d_in[0];
  const float* W0s = (const float*)d_in[1];
  const float* W0n = (const float*)d_in[2];
  const float* W1s = (const float*)d_in[3];
  const float* W1n = (const float*)d_in[4];
  const int*   r0  = (const int*)d_in[5];
  const int*   c0  = (const int*)d_in[6];
  const float* v0  = (const float*)d_in[7];
  const int*   r1  = (const int*)d_in[8];
  const int*   c1  = (const int*)d_in[9];
  const float* v1  = (const float*)d_in[10];
  const float* gam = (const float*)d_in[11];
  const float* bet = (const float*)d_in[12];
  const float* fcW = (const float*)d_in[13];
  const float* fcb = (const float*)d_in[14];
  float* out = (float*)d_out;

  const int H = HDIM;
  const int V = in_sizes[1] / H;     // 30000
  const int B = in_sizes[0] / V;     // 2048
  const int E = in_sizes[5];         // 480000
  const int groups = (V + 31) / 32;  // 938

  // workspace layout (R3)
  char* p = (char*)d_ws;
  int*   cnt0 = (int*)p;               p += (size_t)V * 4;   // memset covers cnt0+cnt1
  int*   cnt1 = (int*)p;               p += (size_t)V * 4;
  unsigned short* ph = (unsigned short*)p;  p += (size_t)groups * 4096 * 2;
  unsigned short* pl = (unsigned short*)p;  p += (size_t)groups * 4096 * 2;
  // region2: se buckets, later aliased by split-K partials P
  char*  region2 = p;
  int2*  se0    = (int2*)region2;                                  // V*CAP*8
  int2*  se1    = se0 + (size_t)V * CAP;                           // V*CAP*8
  float* P      = (float*)region2;     // NSPLIT*B*H*4 = 33.6 MB aliases se

  const int S = NSPLIT;
  const int gps = (groups + S - 1) / S;
  const int DIAG_REPS = 4;             // diagnostic multiplier (see header note)

  hipMemsetAsync(cnt0, 0, (size_t)V * 2 * 4, stream);

  int eblocks = (2 * E + 255) / 256;
  bucket_kernel<<<eblocks, 256, 0, stream>>>(r0, c0, v0, r1, c1, v1,
                                             cnt0, cnt1, se0, se1, E);
  int fblocks = groups * 2;            // half-groups of 16 rows
  fused_glp_kernel<<<fblocks, 1024, 0, stream>>>(W0n, W1n, W0s, W1s,
                                                 cnt0, se0, cnt1, se1,
                                                 gam, bet, ph, pl, V, DIAG_REPS);
  dim3 ggrid(B / 128, S);
  gemm_kernel<<<ggrid, 256, 0, stream>>>(X, ph, pl, P, B, V, groups, gps,
                                         DIAG_REPS);
  fc_kernel<<<B / 16, 256, 0, stream>>>(P, fcW, fcb, out, B * H, S);
}